// Round 1
// baseline (46856.369 us; speedup 1.0000x reference)
//
#include <hip/hip_runtime.h>
#include <math.h>

#define T_LEN 4096
#define HID   1024
#define G4    4096
#define KTAG  50
#define KPAD  64
#define START_TAG 48
#define END_TAG   49
#define NSL   128   // h-slices per direction (8 h outputs per WG)

// ---------------- workspace layout (float-element offsets) ----------------
#define XG_OFF     ((size_t)0)                        // [2][T][4096] f32
#define XG_SZ      ((size_t)2*T_LEN*G4)
#define HOUT_OFF   (XG_OFF + XG_SZ)                   // [2][T][1024] f32
#define HOUT_SZ    ((size_t)2*T_LEN*HID)
#define WT_OFF     (HOUT_OFF + HOUT_SZ)               // [2048][64] f32 (dense_w transposed)
#define WT_SZ      ((size_t)2*HID*KPAD)
#define FEATS_OFF  (WT_OFF + WT_SZ)                   // [T][64] f32
#define FEATS_SZ   ((size_t)T_LEN*KPAD)
#define BP_OFF     (FEATS_OFF + FEATS_SZ)             // [T][64] i32
#define BP_SZ      ((size_t)T_LEN*KPAD)
#define MMAP_OFF   (BP_OFF + BP_SZ)                   // [64][64] i32
#define MMAP_SZ    ((size_t)64*64)
#define ENTRY_OFF  (MMAP_OFF + MMAP_SZ)               // [64] i32
#define BEST_OFF   (ENTRY_OFF + 64)                   // [1] i32
#define FLAGS_OFF  (((BEST_OFF + 1) + 63) & ~(size_t)63) // [2][T][NSL] u32
#define FLAGS_SZ   ((size_t)2*T_LEN*NSL)
#define WS_NEEDED  (((FLAGS_OFF + FLAGS_SZ) * 4))

// =========================================================================
// 1) xg[d][t][r] = sum_h X[t][h]*W_ih[d][r][h] + b_ih[r] + b_hh[r]
//    f32 vector-ALU tiled GEMM, 64x64 tile, 4x4 micro-tile, K-chunk 16.
// =========================================================================
__global__ __launch_bounds__(256, 2) void gemm_xg(
    const float* __restrict__ X, const float* __restrict__ Wf, const float* __restrict__ Wb,
    const float* __restrict__ bihf, const float* __restrict__ bhhf,
    const float* __restrict__ bihb, const float* __restrict__ bhhb,
    float* __restrict__ xg)
{
  const int d  = blockIdx.z;
  const float* __restrict__ W = d ? Wb : Wf;
  const int r0 = blockIdx.x * 64;
  const int t0 = blockIdx.y * 64;
  __shared__ float Xs[16][68];
  __shared__ float Ws[16][68];
  const int tid = threadIdx.x;
  const int tx = tid & 15, ty = tid >> 4;          // out cols r0+tx*4.., rows t0+ty*4..
  const int srow = tid >> 2, skq = (tid & 3) * 4;  // staging: row, k-quad

  float acc[4][4];
#pragma unroll
  for (int i = 0; i < 4; ++i)
#pragma unroll
    for (int j = 0; j < 4; ++j) acc[i][j] = 0.f;

#pragma unroll 1
  for (int k0 = 0; k0 < HID; k0 += 16) {
    const float4 xv = *(const float4*)&X[(size_t)(t0 + srow) * HID + k0 + skq];
    const float4 wv = *(const float4*)&W[(size_t)(r0 + srow) * HID + k0 + skq];
    __syncthreads();
    Xs[skq + 0][srow] = xv.x; Xs[skq + 1][srow] = xv.y; Xs[skq + 2][srow] = xv.z; Xs[skq + 3][srow] = xv.w;
    Ws[skq + 0][srow] = wv.x; Ws[skq + 1][srow] = wv.y; Ws[skq + 2][srow] = wv.z; Ws[skq + 3][srow] = wv.w;
    __syncthreads();
#pragma unroll
    for (int kk = 0; kk < 16; ++kk) {
      const float4 av = *(const float4*)&Xs[kk][ty * 4];
      const float4 bv = *(const float4*)&Ws[kk][tx * 4];
      acc[0][0] += av.x * bv.x; acc[0][1] += av.x * bv.y; acc[0][2] += av.x * bv.z; acc[0][3] += av.x * bv.w;
      acc[1][0] += av.y * bv.x; acc[1][1] += av.y * bv.y; acc[1][2] += av.y * bv.z; acc[1][3] += av.y * bv.w;
      acc[2][0] += av.z * bv.x; acc[2][1] += av.z * bv.y; acc[2][2] += av.z * bv.z; acc[2][3] += av.z * bv.w;
      acc[3][0] += av.w * bv.x; acc[3][1] += av.w * bv.y; acc[3][2] += av.w * bv.z; acc[3][3] += av.w * bv.w;
    }
  }
  const float* __restrict__ b1 = d ? bihb : bihf;
  const float* __restrict__ b2 = d ? bhhb : bhhf;
  float bias[4];
#pragma unroll
  for (int j = 0; j < 4; ++j) bias[j] = b1[r0 + tx * 4 + j] + b2[r0 + tx * 4 + j];
#pragma unroll
  for (int i = 0; i < 4; ++i) {
    float4 v;
    v.x = acc[i][0] + bias[0]; v.y = acc[i][1] + bias[1];
    v.z = acc[i][2] + bias[2]; v.w = acc[i][3] + bias[3];
    *(float4*)&xg[((size_t)d * T_LEN + t0 + ty * 4 + i) * G4 + r0 + tx * 4] = v;
  }
}

// =========================================================================
// 2) Persistent bidirectional LSTM recurrence.
//    256 WGs x 256 thr. WG g: dir d=g>>7, slice s=g&127 owns h[s*8..s*8+8)
//    => 32 rows of w_hh (4 gates x 8) kept in VGPRs (128 regs/lane).
//    Per step: poll 128 slice flags -> load h_prev (4KB) -> swizzled LDS ->
//    reg-resident GEMV (+shfl reduce) -> activations -> publish slice+flag.
// =========================================================================
__global__ __launch_bounds__(256, 1) void lstm_rec(
    const float* __restrict__ xg, const float* __restrict__ whhf,
    const float* __restrict__ whhb, float* __restrict__ hout,
    unsigned* __restrict__ flags)
{
  const int g = blockIdx.x;
  const int d = g >> 7;
  const int s = g & 127;
  const float* __restrict__ whh = d ? whhb : whhf;
  const int tid = threadIdx.x;
  const int sub = tid & 15;   // column group: cols [sub*64, sub*64+64)
  const int rp  = tid >> 4;   // local rows rp and rp+16

  const int lr0 = rp, lr1 = rp + 16;
  const int r0 = ((lr0 >> 3) << 10) + (s << 3) + (lr0 & 7);
  const int r1 = ((lr1 >> 3) << 10) + (s << 3) + (lr1 & 7);

  float w0[64], w1[64];
  {
    const float4* p0 = (const float4*)(whh + (size_t)r0 * HID + sub * 64);
    const float4* p1 = (const float4*)(whh + (size_t)r1 * HID + sub * 64);
#pragma unroll
    for (int b = 0; b < 16; ++b) {
      const float4 v = p0[b];
      w0[4 * b + 0] = v.x; w0[4 * b + 1] = v.y; w0[4 * b + 2] = v.z; w0[4 * b + 3] = v.w;
      const float4 u = p1[b];
      w1[4 * b + 0] = u.x; w1[4 * b + 1] = u.y; w1[4 * b + 2] = u.z; w1[4 * b + 3] = u.w;
    }
  }

  __shared__ float hs[1024];   // swizzled h staging
  __shared__ float gl[32];
  __shared__ float cl[8];
  __shared__ int   abortf[1];
  if (tid < 8) cl[tid] = 0.f;
  if (tid == 0) abortf[0] = 0;
  __syncthreads();

  unsigned* __restrict__ flg = flags + (size_t)d * T_LEN * NSL;
  const float* __restrict__ xgd = xg + (size_t)d * T_LEN * G4;
  // staging slot: element h[G*64+B*4+i] lives at hs[G*64 + ((B+G)&15)*4 + i]
  const int stG = tid >> 4, stB = tid & 15;
  const int stOff = (stG << 6) + ((((stB) + stG) & 15) << 2);

#pragma unroll 1
  for (int it = 0; it < T_LEN; ++it) {
    const int t = d ? (T_LEN - 1 - it) : it;
    float xg0 = 0.f, xg1 = 0.f;
    if (sub == 0) {  // prefetch gate-precompute terms early (hides under poll)
      const float* xr = xgd + (size_t)t * G4;
      xg0 = xr[r0]; xg1 = xr[r1];
    }

    if (it > 0) {
      if (tid < 64) {
        const unsigned* fp = flg + (size_t)(it - 1) * NSL;
        int guard = 1 << 18;
        for (;;) {
          const unsigned f0 = __hip_atomic_load(fp + tid, __ATOMIC_RELAXED, __HIP_MEMORY_SCOPE_AGENT);
          const unsigned f1 = __hip_atomic_load(fp + 64 + tid, __ATOMIC_RELAXED, __HIP_MEMORY_SCOPE_AGENT);
          if (__all(f0 != 0u && f1 != 0u)) break;
          if (--guard == 0) { if (tid == 0) abortf[0] = 1; break; }
          __builtin_amdgcn_s_sleep(2);
        }
        __threadfence();   // acquire: invalidate so h reads see remote XCD writes
      }
      __syncthreads();
      if (abortf[0] != 0) break;   // uniform: bail instead of hanging forever
      const int pt = d ? (t + 1) : (t - 1);
      const float4 hv = *(const float4*)&hout[((size_t)d * T_LEN + pt) * HID + (tid << 2)];
      *(float4*)&hs[stOff] = hv;
    } else {
      *(float4*)&hs[stOff] = make_float4(0.f, 0.f, 0.f, 0.f);
    }
    __syncthreads();

    // reg-resident GEMV: 2 rows x 64 cols per lane, 4 acc chains for ILP
    float a0e = 0.f, a0o = 0.f, a1e = 0.f, a1o = 0.f;
#pragma unroll
    for (int b = 0; b < 16; ++b) {
      const float4 h4 = *(const float4*)&hs[(sub << 6) + (((b + sub) & 15) << 2)];
      if ((b & 1) == 0) {
        a0e += h4.x * w0[4 * b + 0]; a0e += h4.y * w0[4 * b + 1];
        a0e += h4.z * w0[4 * b + 2]; a0e += h4.w * w0[4 * b + 3];
        a1e += h4.x * w1[4 * b + 0]; a1e += h4.y * w1[4 * b + 1];
        a1e += h4.z * w1[4 * b + 2]; a1e += h4.w * w1[4 * b + 3];
      } else {
        a0o += h4.x * w0[4 * b + 0]; a0o += h4.y * w0[4 * b + 1];
        a0o += h4.z * w0[4 * b + 2]; a0o += h4.w * w0[4 * b + 3];
        a1o += h4.x * w1[4 * b + 0]; a1o += h4.y * w1[4 * b + 1];
        a1o += h4.z * w1[4 * b + 2]; a1o += h4.w * w1[4 * b + 3];
      }
    }
    float a0 = a0e + a0o, a1 = a1e + a1o;
#pragma unroll
    for (int m = 1; m < 16; m <<= 1) { a0 += __shfl_xor(a0, m); a1 += __shfl_xor(a1, m); }
    if (sub == 0) { gl[rp] = a0 + xg0; gl[rp + 16] = a1 + xg1; }
    __syncthreads();

    if (tid < 8) {
      const float gi = gl[tid], gf = gl[8 + tid], gg = gl[16 + tid], go = gl[24 + tid];
      const float ii = 1.f / (1.f + expf(-gi));
      const float ff = 1.f / (1.f + expf(-gf));
      const float oo = 1.f / (1.f + expf(-go));
      const float c  = ff * cl[tid] + ii * tanhf(gg);
      const float h  = oo * tanhf(c);
      cl[tid] = c;
      hout[((size_t)d * T_LEN + t) * HID + (s << 3) + tid] = h;
    }
    if (tid < 64) __threadfence();  // release: flush slice before flag (writers are wave 0)
    if (tid == 0)
      __hip_atomic_store(flg + (size_t)it * NSL + s, 1u, __ATOMIC_RELAXED, __HIP_MEMORY_SCOPE_AGENT);
  }
}

// =========================================================================
// 3) dense_w transpose (for coalesced tag-dim reads) and feats GEMM
// =========================================================================
__global__ void transpose_w(const float* __restrict__ dw, float* __restrict__ WT) {
  const int i = blockIdx.x * 256 + threadIdx.x;
  if (i < KTAG * 2 * HID) {
    const int k = i / (2 * HID), h = i % (2 * HID);
    WT[(size_t)h * KPAD + k] = dw[i];
  }
}

__global__ __launch_bounds__(256, 2) void dense_kernel(
    const float* __restrict__ hout, const float* __restrict__ WT,
    const float* __restrict__ db, float* __restrict__ feats)
{
  __shared__ float hrow[4][2048];
  const int tid = threadIdx.x, w = tid >> 6, l = tid & 63;
  const int t = blockIdx.x * 4 + w;
  const float* hf = hout + (size_t)t * HID;
  const float* hb = hout + ((size_t)T_LEN + t) * HID;
#pragma unroll
  for (int c = 0; c < 4; ++c)
    *(float4*)&hrow[w][c * 256 + l * 4] = *(const float4*)&hf[c * 256 + l * 4];
#pragma unroll
  for (int c = 0; c < 4; ++c)
    *(float4*)&hrow[w][1024 + c * 256 + l * 4] = *(const float4*)&hb[c * 256 + l * 4];
  __syncthreads();
  float acc = (l < KTAG) ? db[l] : 0.f;
#pragma unroll 4
  for (int h = 0; h < 2 * HID; h += 4) {
    const float4 hv = *(const float4*)&hrow[w][h];
    acc += hv.x * WT[(size_t)(h + 0) * KPAD + l];
    acc += hv.y * WT[(size_t)(h + 1) * KPAD + l];
    acc += hv.z * WT[(size_t)(h + 2) * KPAD + l];
    acc += hv.w * WT[(size_t)(h + 3) * KPAD + l];
  }
  if (l < KTAG) feats[(size_t)t * KPAD + l] = acc;
}

// =========================================================================
// 4) Viterbi forward scan (single block). 4 waves split the prev range;
//    first-index argmax semantics preserved (ascending, strict >).
// =========================================================================
__global__ __launch_bounds__(256, 1) void viterbi_fwd(
    const float* __restrict__ feats, const float* __restrict__ trans,
    int* __restrict__ bp, float* __restrict__ out, int* __restrict__ best)
{
  __shared__ float tl[KTAG * 53];
  __shared__ float fv[64];
  __shared__ float pm[4][64];
  __shared__ int   pa[4][64];
  const int tid = threadIdx.x, w = tid >> 6, l = tid & 63;
  for (int i = tid; i < KTAG * KTAG; i += 256) tl[(i / KTAG) * 53 + (i % KTAG)] = trans[i];
  if (tid < 64) fv[tid] = (tid == START_TAG) ? 0.f : -10000.f;
  __syncthreads();
  const int P0 = w * 13;
  const int P1 = (P0 + 13 < KTAG) ? (P0 + 13) : KTAG;
#pragma unroll 1
  for (int t = 0; t < T_LEN; ++t) {
    const float ft = (l < KTAG) ? feats[(size_t)t * KPAD + l] : 0.f;
    float m = -3.4e38f; int a = 0;
    if (l < KTAG) {
      for (int p = P0; p < P1; ++p) {
        const float v = tl[l * 53 + p] + fv[p];
        if (v > m) { m = v; a = p; }
      }
    }
    pm[w][l] = m; pa[w][l] = a;
    __syncthreads();
    if (tid < 64) {
      float bm = pm[0][l]; int ba = pa[0][l];
#pragma unroll
      for (int q = 1; q < 4; ++q) {
        const float v = pm[q][l];
        if (v > bm) { bm = v; ba = pa[q][l]; }
      }
      if (l < KTAG) bp[(size_t)t * KPAD + l] = ba;
      fv[l] = bm + ft;
    }
    __syncthreads();
  }
  if (tid < 64) {
    float bv = -3.4e38f; int bi = 1 << 20;
    if (l < KTAG) { bv = fv[l] + tl[END_TAG * 53 + l]; bi = l; }
#pragma unroll
    for (int m = 1; m < 64; m <<= 1) {
      const float ov = __shfl_xor(bv, m);
      const int   oi = __shfl_xor(bi, m);
      if (ov > bv || (ov == bv && oi < bi)) { bv = ov; bi = oi; }
    }
    if (tid == 0) { out[0] = bv; best[0] = bi; }
  }
}

// =========================================================================
// 5) Backtrack via per-chunk map composition (64 chunks of 64 steps)
// =========================================================================
__global__ void bt_chunk(const int* __restrict__ bp, int* __restrict__ mmap) {
  const int c = blockIdx.x, l = threadIdx.x;
  if (l < KTAG) {
    int x = l;
    for (int t = c * 64 + 63; t >= c * 64; --t) x = bp[(size_t)t * KPAD + x];
    mmap[c * 64 + l] = x;
  }
}

__global__ void bt_stitch(const int* __restrict__ mmap, const int* __restrict__ best,
                          int* __restrict__ entry) {
  __shared__ int ml[64 * 64];
  const int tid = threadIdx.x;
  for (int c = 0; c < 64; ++c) ml[c * 64 + tid] = mmap[c * 64 + tid];
  __syncthreads();
  if (tid == 0) {
    int e = best[0];
    for (int c = 63; c >= 0; --c) { entry[c] = e; e = ml[c * 64 + e]; }
  }
}

__global__ void bt_fill(const int* __restrict__ bp, const int* __restrict__ entry,
                        float* __restrict__ out) {
  const int c = blockIdx.x;
  if (threadIdx.x == 0) {
    int x = entry[c];                    // tag at t = c*64+63
    out[1 + c * 64 + 63] = (float)x;
    for (int t = c * 64 + 63; t > c * 64; --t) {
      x = bp[(size_t)t * KPAD + x];
      out[1 + t - 1] = (float)x;
    }
  }
}

// =========================================================================
extern "C" void kernel_launch(void* const* d_in, const int* in_sizes, int n_in,
                              void* d_out, int out_size, void* d_ws, size_t ws_size,
                              hipStream_t stream) {
  (void)in_sizes; (void)n_in; (void)out_size;
  const float* sent  = (const float*)d_in[0];
  const float* wihf  = (const float*)d_in[1];
  const float* whhf  = (const float*)d_in[2];
  const float* bihf  = (const float*)d_in[3];
  const float* bhhf  = (const float*)d_in[4];
  const float* wihb  = (const float*)d_in[5];
  const float* whhb  = (const float*)d_in[6];
  const float* bihb  = (const float*)d_in[7];
  const float* bhhb  = (const float*)d_in[8];
  const float* dw    = (const float*)d_in[9];
  const float* db    = (const float*)d_in[10];
  const float* trans = (const float*)d_in[11];

  if (ws_size < WS_NEEDED) return;   // would need ~175 MB; fail visibly if smaller
  float* ws    = (float*)d_ws;
  float* xg    = ws + XG_OFF;
  float* hout  = ws + HOUT_OFF;
  float* WT    = ws + WT_OFF;
  float* feats = ws + FEATS_OFF;
  int*   bp    = (int*)(ws + BP_OFF);
  int*   mmap  = (int*)(ws + MMAP_OFF);
  int*   entry = (int*)(ws + ENTRY_OFF);
  int*   best  = (int*)(ws + BEST_OFF);
  unsigned* flags = (unsigned*)(ws + FLAGS_OFF);
  float* out = (float*)d_out;

  hipMemsetAsync(flags, 0, FLAGS_SZ * 4, stream);

  hipLaunchKernelGGL(gemm_xg, dim3(64, 64, 2), dim3(256), 0, stream,
                     sent, wihf, wihb, bihf, bhhf, bihb, bhhb, xg);
  hipLaunchKernelGGL(transpose_w, dim3((KTAG * 2 * HID + 255) / 256), dim3(256), 0, stream,
                     dw, WT);
  {
    const float* a0 = xg; const float* a1 = whhf; const float* a2 = whhb;
    float* a3 = hout; unsigned* a4 = flags;
    void* args[] = { (void*)&a0, (void*)&a1, (void*)&a2, (void*)&a3, (void*)&a4 };
    hipError_t ce = hipLaunchCooperativeKernel((void*)lstm_rec, dim3(256), dim3(256),
                                               args, 0, stream);
    if (ce != hipSuccess) {
      // fallback: plain launch (256 WGs x 1/CU are co-resident on a 256-CU MI355X)
      hipLaunchKernelGGL(lstm_rec, dim3(256), dim3(256), 0, stream, a0, a1, a2, a3, a4);
    }
  }
  hipLaunchKernelGGL(dense_kernel, dim3(T_LEN / 4), dim3(256), 0, stream, hout, WT, db, feats);
  hipLaunchKernelGGL(viterbi_fwd, dim3(1), dim3(256), 0, stream, feats, trans, bp, out, best);
  hipLaunchKernelGGL(bt_chunk, dim3(64), dim3(64), 0, stream, bp, mmap);
  hipLaunchKernelGGL(bt_stitch, dim3(1), dim3(64), 0, stream, mmap, best, entry);
  hipLaunchKernelGGL(bt_fill, dim3(64), dim3(64), 0, stream, bp, entry, out);
}

// Round 2
// 21327.620 us; speedup vs baseline: 2.1970x; 2.1970x over previous
//
#include <hip/hip_runtime.h>
#include <math.h>

#define T_LEN 4096
#define HID   1024
#define G4    4096
#define KTAG  50
#define KPAD  64
#define START_TAG 48
#define END_TAG   49
#define NSL   128   // h-slices per direction (8 h outputs per WG)

// ---------------- workspace layout (float-element offsets) ----------------
#define XG_OFF     ((size_t)0)                        // [2][T][4096] f32
#define XG_SZ      ((size_t)2*T_LEN*G4)
#define HOUT_OFF   (XG_OFF + XG_SZ)                   // [2][T][1024] f32
#define HOUT_SZ    ((size_t)2*T_LEN*HID)
#define WT_OFF     (HOUT_OFF + HOUT_SZ)               // [2048][64] f32 (dense_w transposed)
#define WT_SZ      ((size_t)2*HID*KPAD)
#define FEATS_OFF  (WT_OFF + WT_SZ)                   // [T][64] f32
#define FEATS_SZ   ((size_t)T_LEN*KPAD)
#define BP_OFF     (FEATS_OFF + FEATS_SZ)             // [T][64] i32
#define BP_SZ      ((size_t)T_LEN*KPAD)
#define MMAP_OFF   (BP_OFF + BP_SZ)                   // [64][64] i32
#define MMAP_SZ    ((size_t)64*64)
#define ENTRY_OFF  (MMAP_OFF + MMAP_SZ)               // [64] i32
#define BEST_OFF   (ENTRY_OFF + 64)                   // [1] i32
#define FLAGS_OFF  (((BEST_OFF + 1) + 63) & ~(size_t)63) // [2][T][NSL] u32
#define FLAGS_SZ   ((size_t)2*T_LEN*NSL)
#define WS_NEEDED  (((FLAGS_OFF + FLAGS_SZ) * 4))

// =========================================================================
// 1) xg[d][t][r] = sum_h X[t][h]*W_ih[d][r][h] + b_ih[r] + b_hh[r]
// =========================================================================
__global__ __launch_bounds__(256, 2) void gemm_xg(
    const float* __restrict__ X, const float* __restrict__ Wf, const float* __restrict__ Wb,
    const float* __restrict__ bihf, const float* __restrict__ bhhf,
    const float* __restrict__ bihb, const float* __restrict__ bhhb,
    float* __restrict__ xg)
{
  const int d  = blockIdx.z;
  const float* __restrict__ W = d ? Wb : Wf;
  const int r0 = blockIdx.x * 64;
  const int t0 = blockIdx.y * 64;
  __shared__ float Xs[16][68];
  __shared__ float Ws[16][68];
  const int tid = threadIdx.x;
  const int tx = tid & 15, ty = tid >> 4;
  const int srow = tid >> 2, skq = (tid & 3) * 4;

  float acc[4][4];
#pragma unroll
  for (int i = 0; i < 4; ++i)
#pragma unroll
    for (int j = 0; j < 4; ++j) acc[i][j] = 0.f;

#pragma unroll 1
  for (int k0 = 0; k0 < HID; k0 += 16) {
    const float4 xv = *(const float4*)&X[(size_t)(t0 + srow) * HID + k0 + skq];
    const float4 wv = *(const float4*)&W[(size_t)(r0 + srow) * HID + k0 + skq];
    __syncthreads();
    Xs[skq + 0][srow] = xv.x; Xs[skq + 1][srow] = xv.y; Xs[skq + 2][srow] = xv.z; Xs[skq + 3][srow] = xv.w;
    Ws[skq + 0][srow] = wv.x; Ws[skq + 1][srow] = wv.y; Ws[skq + 2][srow] = wv.z; Ws[skq + 3][srow] = wv.w;
    __syncthreads();
#pragma unroll
    for (int kk = 0; kk < 16; ++kk) {
      const float4 av = *(const float4*)&Xs[kk][ty * 4];
      const float4 bv = *(const float4*)&Ws[kk][tx * 4];
      acc[0][0] += av.x * bv.x; acc[0][1] += av.x * bv.y; acc[0][2] += av.x * bv.z; acc[0][3] += av.x * bv.w;
      acc[1][0] += av.y * bv.x; acc[1][1] += av.y * bv.y; acc[1][2] += av.y * bv.z; acc[1][3] += av.y * bv.w;
      acc[2][0] += av.z * bv.x; acc[2][1] += av.z * bv.y; acc[2][2] += av.z * bv.z; acc[2][3] += av.z * bv.w;
      acc[3][0] += av.w * bv.x; acc[3][1] += av.w * bv.y; acc[3][2] += av.w * bv.z; acc[3][3] += av.w * bv.w;
    }
  }
  const float* __restrict__ b1 = d ? bihb : bihf;
  const float* __restrict__ b2 = d ? bhhb : bhhf;
  float bias[4];
#pragma unroll
  for (int j = 0; j < 4; ++j) bias[j] = b1[r0 + tx * 4 + j] + b2[r0 + tx * 4 + j];
#pragma unroll
  for (int i = 0; i < 4; ++i) {
    float4 v;
    v.x = acc[i][0] + bias[0]; v.y = acc[i][1] + bias[1];
    v.z = acc[i][2] + bias[2]; v.w = acc[i][3] + bias[3];
    *(float4*)&xg[((size_t)d * T_LEN + t0 + ty * 4 + i) * G4 + r0 + tx * 4] = v;
  }
}

// =========================================================================
// 2) Persistent bidirectional LSTM recurrence — fence-free release/acquire.
//    All cross-WG data (h values, flags) moves via AGENT-scope relaxed
//    atomics (sc1: write-through / read-through the coherence point).
//    Release ordering = s_waitcnt vmcnt(0) in the producing wave between
//    the h stores and the flag store. NO __threadfence (avoids per-step
//    buffer_wbl2/buffer_inv L2 writeback+invalidate, which was 85% of
//    runtime and 473 GB of HBM re-fetch in round 1).
// =========================================================================
__global__ __launch_bounds__(256, 1) void lstm_rec(
    const float* __restrict__ xg, const float* __restrict__ whhf,
    const float* __restrict__ whhb, float* __restrict__ hout,
    unsigned* __restrict__ flags)
{
  const int g = blockIdx.x;
  const int d = g >> 7;
  const int s = g & 127;
  const float* __restrict__ whh = d ? whhb : whhf;
  const int tid = threadIdx.x;
  const int sub = tid & 15;   // column group: cols [sub*64, sub*64+64)
  const int rp  = tid >> 4;   // local rows rp and rp+16

  const int lr0 = rp, lr1 = rp + 16;
  const int r0 = ((lr0 >> 3) << 10) + (s << 3) + (lr0 & 7);
  const int r1 = ((lr1 >> 3) << 10) + (s << 3) + (lr1 & 7);

  float w0[64], w1[64];
  {
    const float4* p0 = (const float4*)(whh + (size_t)r0 * HID + sub * 64);
    const float4* p1 = (const float4*)(whh + (size_t)r1 * HID + sub * 64);
#pragma unroll
    for (int b = 0; b < 16; ++b) {
      const float4 v = p0[b];
      w0[4 * b + 0] = v.x; w0[4 * b + 1] = v.y; w0[4 * b + 2] = v.z; w0[4 * b + 3] = v.w;
      const float4 u = p1[b];
      w1[4 * b + 0] = u.x; w1[4 * b + 1] = u.y; w1[4 * b + 2] = u.z; w1[4 * b + 3] = u.w;
    }
  }

  __shared__ float hs[1024];   // swizzled h staging
  __shared__ float gl[32];
  __shared__ float cl[8];
  __shared__ int   abortf[1];
  if (tid < 8) cl[tid] = 0.f;
  if (tid == 0) abortf[0] = 0;
  __syncthreads();

  unsigned* __restrict__ flg = flags + (size_t)d * T_LEN * NSL;
  const float* __restrict__ xgd = xg + (size_t)d * T_LEN * G4;
  // staging slot: element h[G*64+B*4+i] lives at hs[G*64 + ((B+G)&15)*4 + i]
  const int stG = tid >> 4, stB = tid & 15;
  const int stOff = (stG << 6) + ((((stB) + stG) & 15) << 2);

#pragma unroll 1
  for (int it = 0; it < T_LEN; ++it) {
    const int t = d ? (T_LEN - 1 - it) : it;
    float xg0 = 0.f, xg1 = 0.f;
    if (sub == 0) {  // prefetch gate-precompute terms early (hides under poll)
      const float* xr = xgd + (size_t)t * G4;
      xg0 = xr[r0]; xg1 = xr[r1];
    }

    if (it > 0) {
      if (tid < 64) {
        const unsigned* fp = flg + (size_t)(it - 1) * NSL;
        int guard = 1 << 18;
        for (;;) {
          const unsigned f0 = __hip_atomic_load(fp + tid, __ATOMIC_RELAXED, __HIP_MEMORY_SCOPE_AGENT);
          const unsigned f1 = __hip_atomic_load(fp + 64 + tid, __ATOMIC_RELAXED, __HIP_MEMORY_SCOPE_AGENT);
          if (__all(f0 != 0u && f1 != 0u)) break;
          if (--guard == 0) { if (tid == 0) abortf[0] = 1; break; }
        }
      }
      __syncthreads();
      if (abortf[0] != 0) break;   // uniform: bail instead of hanging forever
      const int pt = d ? (t + 1) : (t - 1);
      // h data travels through the coherence point: read it with sc1 atomic
      // loads (bypass potentially-stale L1/L2). 2x u64 per lane = 4 floats.
      const unsigned long long* hp =
          (const unsigned long long*)&hout[((size_t)d * T_LEN + pt) * HID + (tid << 2)];
      const unsigned long long q0 = __hip_atomic_load(hp + 0, __ATOMIC_RELAXED, __HIP_MEMORY_SCOPE_AGENT);
      const unsigned long long q1 = __hip_atomic_load(hp + 1, __ATOMIC_RELAXED, __HIP_MEMORY_SCOPE_AGENT);
      float4 hv;
      hv.x = __builtin_bit_cast(float, (unsigned)(q0 & 0xffffffffu));
      hv.y = __builtin_bit_cast(float, (unsigned)(q0 >> 32));
      hv.z = __builtin_bit_cast(float, (unsigned)(q1 & 0xffffffffu));
      hv.w = __builtin_bit_cast(float, (unsigned)(q1 >> 32));
      *(float4*)&hs[stOff] = hv;
    } else {
      *(float4*)&hs[stOff] = make_float4(0.f, 0.f, 0.f, 0.f);
    }
    __syncthreads();

    // reg-resident GEMV: 2 rows x 64 cols per lane, 4 acc chains for ILP
    float a0e = 0.f, a0o = 0.f, a1e = 0.f, a1o = 0.f;
#pragma unroll
    for (int b = 0; b < 16; ++b) {
      const float4 h4 = *(const float4*)&hs[(sub << 6) + (((b + sub) & 15) << 2)];
      if ((b & 1) == 0) {
        a0e += h4.x * w0[4 * b + 0]; a0e += h4.y * w0[4 * b + 1];
        a0e += h4.z * w0[4 * b + 2]; a0e += h4.w * w0[4 * b + 3];
        a1e += h4.x * w1[4 * b + 0]; a1e += h4.y * w1[4 * b + 1];
        a1e += h4.z * w1[4 * b + 2]; a1e += h4.w * w1[4 * b + 3];
      } else {
        a0o += h4.x * w0[4 * b + 0]; a0o += h4.y * w0[4 * b + 1];
        a0o += h4.z * w0[4 * b + 2]; a0o += h4.w * w0[4 * b + 3];
        a1o += h4.x * w1[4 * b + 0]; a1o += h4.y * w1[4 * b + 1];
        a1o += h4.z * w1[4 * b + 2]; a1o += h4.w * w1[4 * b + 3];
      }
    }
    float a0 = a0e + a0o, a1 = a1e + a1o;
#pragma unroll
    for (int m = 1; m < 16; m <<= 1) { a0 += __shfl_xor(a0, m); a1 += __shfl_xor(a1, m); }
    if (sub == 0) { gl[rp] = a0 + xg0; gl[rp + 16] = a1 + xg1; }
    __syncthreads();

    if (tid < 8) {
      const float gi = gl[tid], gf = gl[8 + tid], gg = gl[16 + tid], go = gl[24 + tid];
      const float ii = 1.f / (1.f + expf(-gi));
      const float ff = 1.f / (1.f + expf(-gf));
      const float oo = 1.f / (1.f + expf(-go));
      const float c  = ff * cl[tid] + ii * tanhf(gg);
      const float h  = oo * tanhf(c);
      cl[tid] = c;
      // write-through store: lands at the coherence point, no fence needed
      __hip_atomic_store((unsigned*)&hout[((size_t)d * T_LEN + t) * HID + (s << 3) + tid],
                         __builtin_bit_cast(unsigned, h),
                         __ATOMIC_RELAXED, __HIP_MEMORY_SCOPE_AGENT);
    }
    // release: wave 0 (which issued the 8 h stores, lanes 0..7) waits for
    // them to reach the coherence point, then publishes the flag (sc1).
    asm volatile("s_waitcnt vmcnt(0)" ::: "memory");
    if (tid == 0)
      __hip_atomic_store(flg + (size_t)it * NSL + s, 1u, __ATOMIC_RELAXED, __HIP_MEMORY_SCOPE_AGENT);
  }
}

// =========================================================================
// 3) dense_w transpose (for coalesced tag-dim reads) and feats GEMM
// =========================================================================
__global__ void transpose_w(const float* __restrict__ dw, float* __restrict__ WT) {
  const int i = blockIdx.x * 256 + threadIdx.x;
  if (i < KTAG * 2 * HID) {
    const int k = i / (2 * HID), h = i % (2 * HID);
    WT[(size_t)h * KPAD + k] = dw[i];
  }
}

__global__ __launch_bounds__(256, 2) void dense_kernel(
    const float* __restrict__ hout, const float* __restrict__ WT,
    const float* __restrict__ db, float* __restrict__ feats)
{
  __shared__ float hrow[4][2048];
  const int tid = threadIdx.x, w = tid >> 6, l = tid & 63;
  const int t = blockIdx.x * 4 + w;
  const float* hf = hout + (size_t)t * HID;
  const float* hb = hout + ((size_t)T_LEN + t) * HID;
#pragma unroll
  for (int c = 0; c < 4; ++c)
    *(float4*)&hrow[w][c * 256 + l * 4] = *(const float4*)&hf[c * 256 + l * 4];
#pragma unroll
  for (int c = 0; c < 4; ++c)
    *(float4*)&hrow[w][1024 + c * 256 + l * 4] = *(const float4*)&hb[c * 256 + l * 4];
  __syncthreads();
  float acc = (l < KTAG) ? db[l] : 0.f;
#pragma unroll 4
  for (int h = 0; h < 2 * HID; h += 4) {
    const float4 hv = *(const float4*)&hrow[w][h];
    acc += hv.x * WT[(size_t)(h + 0) * KPAD + l];
    acc += hv.y * WT[(size_t)(h + 1) * KPAD + l];
    acc += hv.z * WT[(size_t)(h + 2) * KPAD + l];
    acc += hv.w * WT[(size_t)(h + 3) * KPAD + l];
  }
  if (l < KTAG) feats[(size_t)t * KPAD + l] = acc;
}

// =========================================================================
// 4) Viterbi forward scan (single block)
// =========================================================================
__global__ __launch_bounds__(256, 1) void viterbi_fwd(
    const float* __restrict__ feats, const float* __restrict__ trans,
    int* __restrict__ bp, float* __restrict__ out, int* __restrict__ best)
{
  __shared__ float tl[KTAG * 53];
  __shared__ float fv[64];
  __shared__ float pm[4][64];
  __shared__ int   pa[4][64];
  const int tid = threadIdx.x, w = tid >> 6, l = tid & 63;
  for (int i = tid; i < KTAG * KTAG; i += 256) tl[(i / KTAG) * 53 + (i % KTAG)] = trans[i];
  if (tid < 64) fv[tid] = (tid == START_TAG) ? 0.f : -10000.f;
  __syncthreads();
  const int P0 = w * 13;
  const int P1 = (P0 + 13 < KTAG) ? (P0 + 13) : KTAG;
#pragma unroll 1
  for (int t = 0; t < T_LEN; ++t) {
    const float ft = (l < KTAG) ? feats[(size_t)t * KPAD + l] : 0.f;
    float m = -3.4e38f; int a = 0;
    if (l < KTAG) {
      for (int p = P0; p < P1; ++p) {
        const float v = tl[l * 53 + p] + fv[p];
        if (v > m) { m = v; a = p; }
      }
    }
    pm[w][l] = m; pa[w][l] = a;
    __syncthreads();
    if (tid < 64) {
      float bm = pm[0][l]; int ba = pa[0][l];
#pragma unroll
      for (int q = 1; q < 4; ++q) {
        const float v = pm[q][l];
        if (v > bm) { bm = v; ba = pa[q][l]; }
      }
      if (l < KTAG) bp[(size_t)t * KPAD + l] = ba;
      fv[l] = bm + ft;
    }
    __syncthreads();
  }
  if (tid < 64) {
    float bv = -3.4e38f; int bi = 1 << 20;
    if (l < KTAG) { bv = fv[l] + tl[END_TAG * 53 + l]; bi = l; }
#pragma unroll
    for (int m = 1; m < 64; m <<= 1) {
      const float ov = __shfl_xor(bv, m);
      const int   oi = __shfl_xor(bi, m);
      if (ov > bv || (ov == bv && oi < bi)) { bv = ov; bi = oi; }
    }
    if (tid == 0) { out[0] = bv; best[0] = bi; }
  }
}

// =========================================================================
// 5) Backtrack via per-chunk map composition (64 chunks of 64 steps)
// =========================================================================
__global__ void bt_chunk(const int* __restrict__ bp, int* __restrict__ mmap) {
  const int c = blockIdx.x, l = threadIdx.x;
  if (l < KTAG) {
    int x = l;
    for (int t = c * 64 + 63; t >= c * 64; --t) x = bp[(size_t)t * KPAD + x];
    mmap[c * 64 + l] = x;
  }
}

__global__ void bt_stitch(const int* __restrict__ mmap, const int* __restrict__ best,
                          int* __restrict__ entry) {
  __shared__ int ml[64 * 64];
  const int tid = threadIdx.x;
  for (int c = 0; c < 64; ++c) ml[c * 64 + tid] = mmap[c * 64 + tid];
  __syncthreads();
  if (tid == 0) {
    int e = best[0];
    for (int c = 63; c >= 0; --c) { entry[c] = e; e = ml[c * 64 + e]; }
  }
}

__global__ void bt_fill(const int* __restrict__ bp, const int* __restrict__ entry,
                        float* __restrict__ out) {
  const int c = blockIdx.x;
  if (threadIdx.x == 0) {
    int x = entry[c];                    // tag at t = c*64+63
    out[1 + c * 64 + 63] = (float)x;
    for (int t = c * 64 + 63; t > c * 64; --t) {
      x = bp[(size_t)t * KPAD + x];
      out[1 + t - 1] = (float)x;
    }
  }
}

// =========================================================================
extern "C" void kernel_launch(void* const* d_in, const int* in_sizes, int n_in,
                              void* d_out, int out_size, void* d_ws, size_t ws_size,
                              hipStream_t stream) {
  (void)in_sizes; (void)n_in; (void)out_size;
  const float* sent  = (const float*)d_in[0];
  const float* wihf  = (const float*)d_in[1];
  const float* whhf  = (const float*)d_in[2];
  const float* bihf  = (const float*)d_in[3];
  const float* bhhf  = (const float*)d_in[4];
  const float* wihb  = (const float*)d_in[5];
  const float* whhb  = (const float*)d_in[6];
  const float* bihb  = (const float*)d_in[7];
  const float* bhhb  = (const float*)d_in[8];
  const float* dw    = (const float*)d_in[9];
  const float* db    = (const float*)d_in[10];
  const float* trans = (const float*)d_in[11];

  if (ws_size < WS_NEEDED) return;
  float* ws    = (float*)d_ws;
  float* xg    = ws + XG_OFF;
  float* hout  = ws + HOUT_OFF;
  float* WT    = ws + WT_OFF;
  float* feats = ws + FEATS_OFF;
  int*   bp    = (int*)(ws + BP_OFF);
  int*   mmap  = (int*)(ws + MMAP_OFF);
  int*   entry = (int*)(ws + ENTRY_OFF);
  int*   best  = (int*)(ws + BEST_OFF);
  unsigned* flags = (unsigned*)(ws + FLAGS_OFF);
  float* out = (float*)d_out;

  hipMemsetAsync(flags, 0, FLAGS_SZ * 4, stream);

  hipLaunchKernelGGL(gemm_xg, dim3(64, 64, 2), dim3(256), 0, stream,
                     sent, wihf, wihb, bihf, bhhf, bihb, bhhb, xg);
  hipLaunchKernelGGL(transpose_w, dim3((KTAG * 2 * HID + 255) / 256), dim3(256), 0, stream,
                     dw, WT);
  {
    const float* a0 = xg; const float* a1 = whhf; const float* a2 = whhb;
    float* a3 = hout; unsigned* a4 = flags;
    void* args[] = { (void*)&a0, (void*)&a1, (void*)&a2, (void*)&a3, (void*)&a4 };
    hipError_t ce = hipLaunchCooperativeKernel((void*)lstm_rec, dim3(256), dim3(256),
                                               args, 0, stream);
    if (ce != hipSuccess) {
      hipLaunchKernelGGL(lstm_rec, dim3(256), dim3(256), 0, stream, a0, a1, a2, a3, a4);
    }
  }
  hipLaunchKernelGGL(dense_kernel, dim3(T_LEN / 4), dim3(256), 0, stream, hout, WT, db, feats);
  hipLaunchKernelGGL(viterbi_fwd, dim3(1), dim3(256), 0, stream, feats, trans, bp, out, best);
  hipLaunchKernelGGL(bt_chunk, dim3(64), dim3(64), 0, stream, bp, mmap);
  hipLaunchKernelGGL(bt_stitch, dim3(1), dim3(64), 0, stream, mmap, best, entry);
  hipLaunchKernelGGL(bt_fill, dim3(64), dim3(64), 0, stream, bp, entry, out);
}